// Round 5
// baseline (1006.132 us; speedup 1.0000x reference)
//
#include <hip/hip_runtime.h>
#include <cstdint>
#include <cstddef>

#define DEV __device__ __forceinline__

typedef __attribute__((ext_vector_type(8))) __bf16 bf16x8;
typedef __attribute__((ext_vector_type(4))) float f32x4;
typedef __attribute__((ext_vector_type(4))) uint32_t u32x4;

// Problem constants
constexpr int BB = 2, SS = 2048, DMOD = 1024, HH = 16, DDEP = 64;
constexpr int MM = BB * SS;          // 4096 rows for the projection GEMMs
constexpr float SCL = 0.125f;        // 1/sqrt(64)

// Workspace layout (bytes). Peak 56 MB via aliasing.
constexpr size_t SZ_ACT = (size_t)MM * DMOD * 2;   // 8 MB
constexpr size_t SZ_W = (size_t)DMOD * DMOD * 2;   // 2 MB
constexpr size_t OFF_QB = 0;
constexpr size_t OFF_KB = OFF_QB + SZ_ACT;
constexpr size_t OFF_VB = OFF_KB + SZ_ACT;
constexpr size_t OFF_WQT = OFF_VB + SZ_ACT;
constexpr size_t OFF_WKT = OFF_WQT + SZ_W;
constexpr size_t OFF_WVT = OFF_WKT + SZ_W;
constexpr size_t OFF_WOT = OFF_WVT + SZ_W;
constexpr size_t OFF_QH = OFF_WOT + SZ_W;
constexpr size_t OFF_KH = OFF_QH + SZ_ACT;
constexpr size_t OFF_VH = OFF_KH + SZ_ACT;
constexpr size_t OFF_VHT = OFF_QB;                 // alias (qb dead)
constexpr size_t OFF_CTX = OFF_KB;                 // alias (kb dead)

DEV uint16_t f2bf(float f) {
  uint32_t u = __builtin_bit_cast(uint32_t, f);
  u += 0x7fffu + ((u >> 16) & 1u);   // RNE
  return (uint16_t)(u >> 16);
}
DEV uint32_t pk2(float a, float b) { return (uint32_t)f2bf(a) | ((uint32_t)f2bf(b) << 16); }
DEV f32x4 mfma16(bf16x8 a, bf16x8 b, f32x4 c) {
  return __builtin_amdgcn_mfma_f32_16x16x32_bf16(a, b, c, 0, 0, 0);
}
// async global->LDS, 16B per lane. LDS dest = wave-uniform base + lane*16 (m104).
DEV void gload16(const void* g, void* l) {
  __builtin_amdgcn_global_load_lds(
      (const __attribute__((address_space(1))) void*)g,
      (__attribute__((address_space(3))) void*)l, 16, 0, 0);
}
// P-tile byte swizzle: row bits 0-2 -> byte bits 5-7, row bit 3 -> byte bit 4.
// Gives full 8-bank-group coverage for 16B/32B-strided reads (audit R3).
DEV int pswz(int row) { return ((row & 7) << 5) ^ ((row & 8) << 1); }

// ---------------------------------------------------------------- cast fp32 -> bf16 (8 elems/thread)
__global__ __launch_bounds__(256) void cast_bf16(const float4* __restrict__ in, u32x4* __restrict__ out) {
  size_t i = (size_t)blockIdx.x * 256 + threadIdx.x;
  float4 a = in[i * 2], b = in[i * 2 + 1];
  u32x4 o;
  o.x = pk2(a.x, a.y); o.y = pk2(a.z, a.w);
  o.z = pk2(b.x, b.y); o.w = pk2(b.z, b.w);
  out[i] = o;
}

// ---------------------------------------------------------------- W [K][N] fp32 -> W^T [N][K] bf16
__global__ __launch_bounds__(256) void wtrans(const float* __restrict__ W, uint16_t* __restrict__ WT) {
  __shared__ uint16_t tile[64 * 72];
  const int kb = blockIdx.x * 64, nb = blockIdx.y * 64;
  const int t = threadIdx.x;
  {
    const int kl = t >> 2, nc = (t & 3) * 16;
    const float4* src = reinterpret_cast<const float4*>(&W[(size_t)(kb + kl) * DMOD + nb + nc]);
    float4 v0 = src[0], v1 = src[1], v2 = src[2], v3 = src[3];
    uint16_t* d = &tile[kl * 72 + nc];
    d[0] = f2bf(v0.x); d[1] = f2bf(v0.y); d[2] = f2bf(v0.z); d[3] = f2bf(v0.w);
    d[4] = f2bf(v1.x); d[5] = f2bf(v1.y); d[6] = f2bf(v1.z); d[7] = f2bf(v1.w);
    d[8] = f2bf(v2.x); d[9] = f2bf(v2.y); d[10] = f2bf(v2.z); d[11] = f2bf(v2.w);
    d[12] = f2bf(v3.x); d[13] = f2bf(v3.y); d[14] = f2bf(v3.z); d[15] = f2bf(v3.w);
  }
  __syncthreads();
  {
    const int n = t >> 2, kc = (t & 3) * 16;
    uint16_t r[16];
#pragma unroll
    for (int j = 0; j < 16; ++j) r[j] = tile[(kc + j) * 72 + n];
    u32x4 o0, o1;
    o0.x = r[0] | ((uint32_t)r[1] << 16);  o0.y = r[2] | ((uint32_t)r[3] << 16);
    o0.z = r[4] | ((uint32_t)r[5] << 16);  o0.w = r[6] | ((uint32_t)r[7] << 16);
    o1.x = r[8] | ((uint32_t)r[9] << 16);  o1.y = r[10] | ((uint32_t)r[11] << 16);
    o1.z = r[12] | ((uint32_t)r[13] << 16); o1.w = r[14] | ((uint32_t)r[15] << 16);
    uint16_t* dst = &WT[(size_t)(nb + n) * DMOD + kb + kc];
    *reinterpret_cast<u32x4*>(dst) = o0;
    *reinterpret_cast<u32x4*>(dst + 8) = o1;
  }
}

// ---------------------------------------------------------------- Vh [B,S,H,D] -> VhT [B*H, D, S] (bf16)
__global__ __launch_bounds__(256) void vtrans(const uint16_t* __restrict__ Vh, uint16_t* __restrict__ VhT) {
  __shared__ uint16_t tile[64 * 72];
  const int sb = blockIdx.x * 64;
  const int bh = blockIdx.y;
  const int b = bh >> 4, h = bh & 15;
  const int t = threadIdx.x;
  {
    const int sl = t >> 2, dc = (t & 3) * 16;
    const u32x4* src = reinterpret_cast<const u32x4*>(&Vh[(size_t)(b * SS + sb + sl) * DMOD + h * DDEP + dc]);
    *reinterpret_cast<u32x4*>(&tile[sl * 72 + dc]) = src[0];
    *reinterpret_cast<u32x4*>(&tile[sl * 72 + dc + 8]) = src[1];
  }
  __syncthreads();
  {
    const int d = t >> 2, sc = (t & 3) * 16;
    uint16_t r[16];
#pragma unroll
    for (int j = 0; j < 16; ++j) r[j] = tile[(sc + j) * 72 + d];
    u32x4 o0, o1;
    o0.x = r[0] | ((uint32_t)r[1] << 16);  o0.y = r[2] | ((uint32_t)r[3] << 16);
    o0.z = r[4] | ((uint32_t)r[5] << 16);  o0.w = r[6] | ((uint32_t)r[7] << 16);
    o1.x = r[8] | ((uint32_t)r[9] << 16);  o1.y = r[10] | ((uint32_t)r[11] << 16);
    o1.z = r[12] | ((uint32_t)r[13] << 16); o1.w = r[14] | ((uint32_t)r[15] << 16);
    uint16_t* dst = &VhT[((size_t)bh * DDEP + d) * SS + sb + sc];
    *reinterpret_cast<u32x4*>(dst) = o0;
    *reinterpret_cast<u32x4*>(dst + 8) = o1;
  }
}

// ---------------------------------------------------------------- C = A @ B^T + bias
// 64x64 tile, 4 waves each 32x32, BK=64. global_load_lds staging with
// pre-swizzled source (chunk c holds global chunk c^(row&7); involution).
template <int OUTF32>
__global__ __launch_bounds__(256, 4) void gemm_bt(
    const uint16_t* __restrict__ A, const uint16_t* __restrict__ Bt,
    const float* __restrict__ bias, void* __restrict__ Cout,
    int Md, int Nd, int Kd) {
  __shared__ uint16_t As[64 * 64];
  __shared__ uint16_t Bs[64 * 64];
  const int t = threadIdx.x;
  const int lane = t & 63, w = t >> 6;
  const int wr = w >> 1, wc = w & 1;
  const int g = lane >> 4, c16 = lane & 15;
  const int ntiles = Nd >> 6;
  const int nwg = (Md >> 6) * ntiles;          // multiple of 8 here
  int bid = blockIdx.x;
  bid = (bid & 7) * (nwg >> 3) + (bid >> 3);   // bijective XCD swizzle
  const int mt = bid / ntiles, nt = bid % ntiles;
  char* AsB = reinterpret_cast<char*>(As);
  char* BsB = reinterpret_cast<char*>(Bs);

  // staging geometry: instr i covers rows i*32 + w*8 + (lane>>3), chunk lane&7
  const int srow = w * 8 + (lane >> 3);
  const int schunk0 = lane & 7;

  f32x4 acc[2][2] = {};
  const int nkt = Kd >> 6;
  for (int kt = 0; kt < nkt; ++kt) {
#pragma unroll
    for (int i = 0; i < 2; ++i) {
      int row = i * 32 + srow;
      int cs = schunk0 ^ (row & 7);
      gload16(A + (size_t)(mt * 64 + row) * Kd + kt * 64 + cs * 8,
              AsB + i * 4096 + w * 1024);
      gload16(Bt + (size_t)(nt * 64 + row) * Kd + kt * 64 + cs * 8,
              BsB + i * 4096 + w * 1024);
    }
    __syncthreads();   // drains vmcnt before barrier (compiler-inserted)
#pragma unroll
    for (int kk = 0; kk < 2; ++kk) {
      bf16x8 af[2], bfr[2];
#pragma unroll
      for (int mf = 0; mf < 2; ++mf) {
        int row = wr * 32 + mf * 16 + c16;
        af[mf] = *reinterpret_cast<const bf16x8*>(
            AsB + row * 128 + ((kk * 4 + g) ^ (row & 7)) * 16);
      }
#pragma unroll
      for (int nf = 0; nf < 2; ++nf) {
        int row = wc * 32 + nf * 16 + c16;
        bfr[nf] = *reinterpret_cast<const bf16x8*>(
            BsB + row * 128 + ((kk * 4 + g) ^ (row & 7)) * 16);
      }
#pragma unroll
      for (int mf = 0; mf < 2; ++mf)
#pragma unroll
        for (int nf = 0; nf < 2; ++nf)
          acc[mf][nf] = mfma16(af[mf], bfr[nf], acc[mf][nf]);
    }
    __syncthreads();
  }
  float bv[2];
#pragma unroll
  for (int nf = 0; nf < 2; ++nf) bv[nf] = bias[nt * 64 + wc * 32 + nf * 16 + c16];
#pragma unroll
  for (int mf = 0; mf < 2; ++mf)
#pragma unroll
    for (int nf = 0; nf < 2; ++nf)
#pragma unroll
      for (int r = 0; r < 4; ++r) {
        int row = mt * 64 + wr * 32 + mf * 16 + g * 4 + r;
        int col = nt * 64 + wc * 32 + nf * 16 + c16;
        float v0 = acc[mf][nf][r] + bv[nf];
        if (OUTF32)
          reinterpret_cast<float*>(Cout)[(size_t)row * Nd + col] = v0;
        else
          reinterpret_cast<uint16_t*>(Cout)[(size_t)row * Nd + col] = f2bf(v0);
      }
}

// ---------------------------------------------------------------- fused scores+softmax+attn-write+PV
// grid: 1024 blocks = (b,h) x 32 q-tiles of 64 rows; 4 waves x 16 q-rows.
// Two-pass online softmax; pass 2 stages normalized P (f32) in per-wave LDS,
// emits coalesced float4 attn stores, and feeds PV from the same tile.
__global__ __launch_bounds__(256, 4) void attn_fused(
    const uint16_t* __restrict__ Qh, const uint16_t* __restrict__ Kh,
    const uint16_t* __restrict__ VhT, const float* __restrict__ mask,
    float* __restrict__ attn, uint16_t* __restrict__ ctx) {
  __shared__ float Plds[4 * 16 * 128];  // 8KB per wave, f32, XOR-swizzled rows
  const int t = threadIdx.x;
  const int lane = t & 63, w = t >> 6;
  const int g = lane >> 4, c16 = lane & 15;
  int bid = blockIdx.x;
  bid = (bid & 7) * 128 + (bid >> 3);   // XCD swizzle: 4 heads per XCD
  const int bh = bid >> 5, qt = bid & 31;
  const int b = bh >> 4, h = bh & 15;

  const uint16_t* Qbase = Qh + ((size_t)(b * SS + qt * 64 + w * 16)) * DMOD + h * DDEP;
  const uint16_t* Kbase = Kh + ((size_t)b * SS) * DMOD + h * DDEP;
  const uint16_t* Vbase = VhT + (size_t)bh * DDEP * SS;
  const float* mbase = mask + (size_t)b * SS;
  char* Pw = reinterpret_cast<char*>(Plds) + w * (16 * 512);

  // Q fragments (16 rows) in registers for the whole kernel
  bf16x8 qf[2];
#pragma unroll
  for (int kk = 0; kk < 2; ++kk)
    qf[kk] = *reinterpret_cast<const bf16x8*>(Qbase + (size_t)c16 * DMOD + kk * 32 + g * 8);

  float m_[4], l_[4];
#pragma unroll
  for (int r = 0; r < 4; ++r) { m_[r] = -3.0e38f; l_[r] = 0.f; }

  // ---- pass 1: online (m, l)
  for (int kt = 0; kt < 16; ++kt) {
    f32x4 sacc[8] = {};
#pragma unroll
    for (int nf = 0; nf < 8; ++nf) {
      const uint16_t* kp = Kbase + (size_t)(kt * 128 + nf * 16 + c16) * DMOD + g * 8;
      bf16x8 b0 = *reinterpret_cast<const bf16x8*>(kp);
      bf16x8 b1 = *reinterpret_cast<const bf16x8*>(kp + 32);
      sacc[nf] = mfma16(qf[0], b0, sacc[nf]);
      sacc[nf] = mfma16(qf[1], b1, sacc[nf]);
    }
    float mv[8];
#pragma unroll
    for (int nf = 0; nf < 8; ++nf) mv[nf] = mbase[kt * 128 + nf * 16 + c16] * -1e9f;
#pragma unroll
    for (int r = 0; r < 4; ++r) {
      float tm = -3.0e38f;
#pragma unroll
      for (int nf = 0; nf < 8; ++nf) {
        float sv = sacc[nf][r] * SCL + mv[nf];
        sacc[nf][r] = sv;
        tm = fmaxf(tm, sv);
      }
#pragma unroll
      for (int d = 1; d < 16; d <<= 1) tm = fmaxf(tm, __shfl_xor(tm, d));
      float mo = m_[r];
      float mn = fmaxf(mo, tm);
      float sum = 0.f;
#pragma unroll
      for (int nf = 0; nf < 8; ++nf) sum += __expf(sacc[nf][r] - mn);
#pragma unroll
      for (int d = 1; d < 16; d <<= 1) sum += __shfl_xor(sum, d);
      l_[r] = l_[r] * __expf(mo - mn) + sum;
      m_[r] = mn;
    }
  }
  float li[4];
#pragma unroll
  for (int r = 0; r < 4; ++r) li[r] = 1.f / l_[r];

  // ---- pass 2: recompute scores, stage P in LDS f32, coalesced attn store, PV
  f32x4 cacc[4] = {};
  float* abase = attn + ((size_t)bh * SS + qt * 64 + w * 16) * SS;

  for (int kt = 0; kt < 16; ++kt) {
    f32x4 sacc[8] = {};
#pragma unroll
    for (int nf = 0; nf < 8; ++nf) {
      const uint16_t* kp = Kbase + (size_t)(kt * 128 + nf * 16 + c16) * DMOD + g * 8;
      bf16x8 b0 = *reinterpret_cast<const bf16x8*>(kp);
      bf16x8 b1 = *reinterpret_cast<const bf16x8*>(kp + 32);
      sacc[nf] = mfma16(qf[0], b0, sacc[nf]);
      sacc[nf] = mfma16(qf[1], b1, sacc[nf]);
    }
    float mv[8];
#pragma unroll
    for (int nf = 0; nf < 8; ++nf) mv[nf] = mbase[kt * 128 + nf * 16 + c16] * -1e9f;
    // normalized P -> LDS (f32; addr = row*512 + (col*4 ^ pswz(row)))
#pragma unroll
    for (int nf = 0; nf < 8; ++nf)
#pragma unroll
      for (int r = 0; r < 4; ++r) {
        int pr = g * 4 + r;
        float p = __expf(sacc[nf][r] * SCL + mv[nf] - m_[r]) * li[r];
        *reinterpret_cast<float*>(
            Pw + pr * 512 + (((nf * 16 + c16) * 4) ^ pswz(pr))) = p;
      }
    // coalesced attn store: 8 instrs x (64 lanes x 16B); rows in pairs
#pragma unroll
    for (int i = 0; i < 8; ++i) {
      int row = i * 2 + (lane >> 5);
      int cc = lane & 31;
      float4 val = *reinterpret_cast<const float4*>(
          Pw + row * 512 + ((cc * 16) ^ pswz(row)));
      *reinterpret_cast<float4*>(abase + (size_t)row * SS + kt * 128 + cc * 4) = val;
    }
    // PV: ctx(16x64) += P(16x128) @ V^T-slice; A-frag from LDS f32 -> bf16.
    // NOTE: each 16B block's address is XORed independently (carry hazard
    // when pswz bit 4 is set — audited R3).
#pragma unroll
    for (int ks = 0; ks < 4; ++ks) {
      const char* prow = Pw + c16 * 512;
      f32x4 p0 = *reinterpret_cast<const f32x4*>(prow + ((ks * 128 + g * 32) ^ pswz(c16)));
      f32x4 p1 = *reinterpret_cast<const f32x4*>(prow + ((ks * 128 + g * 32 + 16) ^ pswz(c16)));
      union { bf16x8 v; uint16_t u[8]; } pa;
#pragma unroll
      for (int j = 0; j < 4; ++j) { pa.u[j] = f2bf(p0[j]); pa.u[4 + j] = f2bf(p1[j]); }
#pragma unroll
      for (int nf = 0; nf < 4; ++nf) {
        bf16x8 vf = *reinterpret_cast<const bf16x8*>(
            Vbase + (size_t)(nf * 16 + c16) * SS + kt * 128 + ks * 32 + g * 8);
        cacc[nf] = mfma16(pa.v, vf, cacc[nf]);
      }
    }
  }
  // ctx write: [B,S,H*D] bf16
#pragma unroll
  for (int nf = 0; nf < 4; ++nf)
#pragma unroll
    for (int r = 0; r < 4; ++r) {
      int row = qt * 64 + w * 16 + g * 4 + r;
      ctx[((size_t)(b * SS + row)) * DMOD + h * DDEP + nf * 16 + c16] = f2bf(cacc[nf][r]);
    }
}

// ----------------------------------------------------------------
extern "C" void kernel_launch(void* const* d_in, const int* in_sizes, int n_in,
                              void* d_out, int out_size, void* d_ws, size_t ws_size,
                              hipStream_t stream) {
  (void)in_sizes; (void)n_in; (void)out_size; (void)ws_size;
  const float* q = (const float*)d_in[0];
  const float* k = (const float*)d_in[1];
  const float* v = (const float*)d_in[2];
  const float* mask = (const float*)d_in[3];
  const float* wq = (const float*)d_in[4];
  const float* bq = (const float*)d_in[5];
  const float* wk = (const float*)d_in[6];
  const float* bk = (const float*)d_in[7];
  const float* wv = (const float*)d_in[8];
  const float* bvv = (const float*)d_in[9];
  const float* wo = (const float*)d_in[10];
  const float* bo = (const float*)d_in[11];

  char* ws = (char*)d_ws;
  uint16_t* qb = (uint16_t*)(ws + OFF_QB);
  uint16_t* kb = (uint16_t*)(ws + OFF_KB);
  uint16_t* vb = (uint16_t*)(ws + OFF_VB);
  uint16_t* wqT = (uint16_t*)(ws + OFF_WQT);
  uint16_t* wkT = (uint16_t*)(ws + OFF_WKT);
  uint16_t* wvT = (uint16_t*)(ws + OFF_WVT);
  uint16_t* woT = (uint16_t*)(ws + OFF_WOT);
  uint16_t* Qhp = (uint16_t*)(ws + OFF_QH);
  uint16_t* Khp = (uint16_t*)(ws + OFF_KH);
  uint16_t* Vhp = (uint16_t*)(ws + OFF_VH);
  uint16_t* VhTp = (uint16_t*)(ws + OFF_VHT);
  uint16_t* ctxp = (uint16_t*)(ws + OFF_CTX);

  float* outp = (float*)d_out;
  float* attnp = outp + (size_t)MM * DMOD;

  cast_bf16<<<2048, 256, 0, stream>>>((const float4*)q, (u32x4*)qb);
  cast_bf16<<<2048, 256, 0, stream>>>((const float4*)k, (u32x4*)kb);
  cast_bf16<<<2048, 256, 0, stream>>>((const float4*)v, (u32x4*)vb);
  wtrans<<<dim3(16, 16), 256, 0, stream>>>(wq, wqT);
  wtrans<<<dim3(16, 16), 256, 0, stream>>>(wk, wkT);
  wtrans<<<dim3(16, 16), 256, 0, stream>>>(wv, wvT);
  wtrans<<<dim3(16, 16), 256, 0, stream>>>(wo, woT);
  // QKV projections: 1024 blocks each (64x64 tiles, 4/CU)
  gemm_bt<0><<<1024, 256, 0, stream>>>(qb, wqT, bq, Qhp, MM, DMOD, DMOD);
  gemm_bt<0><<<1024, 256, 0, stream>>>(kb, wkT, bk, Khp, MM, DMOD, DMOD);
  gemm_bt<0><<<1024, 256, 0, stream>>>(vb, wvT, bvv, Vhp, MM, DMOD, DMOD);
  vtrans<<<dim3(32, 32), 256, 0, stream>>>(Vhp, VhTp);
  // fused attention: 1024 blocks (4/CU)
  attn_fused<<<1024, 256, 0, stream>>>(Qhp, Khp, VhTp, mask, attnp, ctxp);
  // output projection
  gemm_bt<1><<<1024, 256, 0, stream>>>(ctxp, woT, bo, d_out, MM, DMOD, DMOD);
}